// Round 1
// baseline (417.339 us; speedup 1.0000x reference)
//
#include <hip/hip_runtime.h>
#include <math.h>

// Problem constants (validated against in_sizes at launch where cheap):
//   N_SRC=N_DST=10000, E=320000, T=4, C=64
// Row = (node, t) pair; C=64 = one wave's lanes.

__global__ __launch_bounds__(256) void proj_kernel(
    const float* __restrict__ in, const float* __restrict__ W,
    float* __restrict__ out, int nrows) {
    // out[r, c] = sum_k in[r, k] * W[k, c]; one row per 64-lane wave, 4 rows/block.
    __shared__ float sW[64 * 64];
    int tid = threadIdx.x;
#pragma unroll
    for (int i = 0; i < 16; ++i) sW[tid + i * 256] = W[tid + i * 256];
    __syncthreads();

    int c = tid & 63;
    int r = blockIdx.x * 4 + (tid >> 6);
    if (r >= nrows) return;

    float a = in[(size_t)r * 64 + c];   // coalesced: lane c loads element c
    float acc = 0.f;
#pragma unroll
    for (int k = 0; k < 64; ++k) {
        acc += __shfl(a, k, 64) * sW[k * 64 + c];  // broadcast row elem k; LDS stride-1 (2-way, free)
    }
    out[(size_t)r * 64 + c] = acc;
}

__global__ __launch_bounds__(256) void edge_kernel(
    const float* __restrict__ h_src, const float* __restrict__ h_dst,
    const float* __restrict__ edge_weight, const float* __restrict__ weight_e,
    const int* __restrict__ src_idx, const int* __restrict__ dst_idx,
    float* __restrict__ aggr, int E) {
    // One block per edge. Lane layout: t = tid>>6 (T=4), c = tid&63 (C=64).
    __shared__ float swe[64];
    int tid = threadIdx.x;
    if (tid < 64) swe[tid] = weight_e[tid];
    __syncthreads();

    int e = blockIdx.x;
    if (e >= E) return;
    int t = tid >> 6;
    int c = tid & 63;

    int s = src_idx[e];          // wave-uniform broadcast loads
    int d = dst_idx[e];
    float w = edge_weight[e];

    float hs = h_src[((size_t)s * 4 + t) * 64 + c];  // 256B coalesced per wave
    float hd = h_dst[((size_t)d * 4 + t) * 64 + c];
    float x = hs * hd * (w * swe[c]);
    float g = 1.f / (1.f + __expf(-x));              // sigmoid
    atomicAdd(&aggr[((size_t)d * 4 + t) * 64 + c], hs * g);
}

__global__ __launch_bounds__(256) void ln_kernel(
    const float* __restrict__ aggr, const float* __restrict__ feat_dst,
    const float* __restrict__ gamma, const float* __restrict__ beta,
    float* __restrict__ out, int nrows) {
    // One row per wave; mean/var via 64-lane butterfly.
    int tid = threadIdx.x;
    int c = tid & 63;
    int r = blockIdx.x * 4 + (tid >> 6);
    if (r >= nrows) return;

    size_t base = (size_t)r * 64;
    float v = aggr[base + c];
    float s = v, s2 = v * v;
#pragma unroll
    for (int off = 32; off >= 1; off >>= 1) {
        s += __shfl_xor(s, off, 64);
        s2 += __shfl_xor(s2, off, 64);
    }
    float mean = s * (1.f / 64.f);
    float var = s2 * (1.f / 64.f) - mean * mean;
    float inv = rsqrtf(var + 1e-5f);
    out[base + c] = (v - mean) * inv * gamma[c] + beta[c] + feat_dst[base + c];
}

extern "C" void kernel_launch(void* const* d_in, const int* in_sizes, int n_in,
                              void* d_out, int out_size, void* d_ws, size_t ws_size,
                              hipStream_t stream) {
    const float* feat_src    = (const float*)d_in[0];
    const float* feat_dst    = (const float*)d_in[1];
    const float* edge_weight = (const float*)d_in[2];
    const float* weight_e    = (const float*)d_in[3];
    const float* u           = (const float*)d_in[4];
    const float* v           = (const float*)d_in[5];
    const float* ln_gamma    = (const float*)d_in[6];
    const float* ln_beta     = (const float*)d_in[7];
    const int*   src_idx     = (const int*)d_in[8];
    const int*   dst_idx     = (const int*)d_in[9];
    float* out = (float*)d_out;

    int E          = in_sizes[2];
    int n_src_rows = in_sizes[0] / 64;   // N_SRC * T
    int n_dst_rows = in_sizes[1] / 64;   // N_DST * T

    // Workspace layout (fp32): h_src | h_dst | aggr  (~30.7 MB total)
    float* h_src = (float*)d_ws;
    float* h_dst = h_src + (size_t)n_src_rows * 64;
    float* aggr  = h_dst + (size_t)n_dst_rows * 64;

    // 1) Projections. aggr is seeded with feat_dst @ u (the "out" base term),
    //    so the edge kernel just accumulates messages on top — every ws byte
    //    we read is freshly written each call (poison-safe).
    proj_kernel<<<(n_src_rows + 3) / 4, 256, 0, stream>>>(feat_src, u, h_src, n_src_rows);
    proj_kernel<<<(n_dst_rows + 3) / 4, 256, 0, stream>>>(feat_dst, v, h_dst, n_dst_rows);
    proj_kernel<<<(n_dst_rows + 3) / 4, 256, 0, stream>>>(feat_dst, u, aggr, n_dst_rows);

    // 2) Edge gather -> gate -> scatter-add (atomic).
    edge_kernel<<<E, 256, 0, stream>>>(h_src, h_dst, edge_weight, weight_e,
                                       src_idx, dst_idx, aggr, E);

    // 3) LayerNorm + residual epilogue.
    ln_kernel<<<(n_dst_rows + 3) / 4, 256, 0, stream>>>(aggr, feat_dst, ln_gamma, ln_beta,
                                                        out, n_dst_rows);
}

// Round 2
// 243.408 us; speedup vs baseline: 1.7146x; 1.7146x over previous
//
#include <hip/hip_runtime.h>
#include <math.h>

// N_SRC=N_DST=10000, E=320000, T=4, C=64. Row=(node,t); C=64 = one wave.
// Pipeline: proj(feat_src@u) | proj_dual(feat_dst@{u,v}) | zero|hist|scan|scatter
// (counting sort of edges by dst) | aggregate (register accum + fused LN+residual).

__global__ __launch_bounds__(256) void proj_kernel(
    const float* __restrict__ in, const float* __restrict__ W,
    float* __restrict__ out, int nrows) {
    __shared__ float sW[64 * 64];
    int tid = threadIdx.x;
#pragma unroll
    for (int i = 0; i < 16; ++i) sW[tid + i * 256] = W[tid + i * 256];
    __syncthreads();
    int c = tid & 63;
    int r = blockIdx.x * 4 + (tid >> 6);
    if (r >= nrows) return;
    float a = in[(size_t)r * 64 + c];
    float acc = 0.f;
#pragma unroll
    for (int k = 0; k < 64; ++k)
        acc += __shfl(a, k, 64) * sW[k * 64 + c];
    out[(size_t)r * 64 + c] = acc;
}

__global__ __launch_bounds__(256) void proj_dual_kernel(
    const float* __restrict__ in, const float* __restrict__ U, const float* __restrict__ V,
    float* __restrict__ outU, float* __restrict__ outV, int nrows) {
    __shared__ float sU[64 * 64];
    __shared__ float sV[64 * 64];
    int tid = threadIdx.x;
#pragma unroll
    for (int i = 0; i < 16; ++i) {
        sU[tid + i * 256] = U[tid + i * 256];
        sV[tid + i * 256] = V[tid + i * 256];
    }
    __syncthreads();
    int c = tid & 63;
    int r = blockIdx.x * 4 + (tid >> 6);
    if (r >= nrows) return;
    float a = in[(size_t)r * 64 + c];
    float accU = 0.f, accV = 0.f;
#pragma unroll
    for (int k = 0; k < 64; ++k) {
        float b = __shfl(a, k, 64);
        accU += b * sU[k * 64 + c];
        accV += b * sV[k * 64 + c];
    }
    outU[(size_t)r * 64 + c] = accU;
    outV[(size_t)r * 64 + c] = accV;
}

__global__ void zero_kernel(int* __restrict__ p, int n) {
    int i = blockIdx.x * blockDim.x + threadIdx.x;
    if (i < n) p[i] = 0;
}

__global__ void hist_kernel(const int* __restrict__ dst_idx, int E, int* __restrict__ counts) {
    int e = blockIdx.x * blockDim.x + threadIdx.x;
    if (e < E) atomicAdd(&counts[dst_idx[e]], 1);
}

// Single-block exclusive scan of counts[0..n) -> offsets[0..n], plus cursor copy.
__global__ __launch_bounds__(256) void scan_kernel(
    const int* __restrict__ counts, int n,
    int* __restrict__ offsets, int* __restrict__ cursor) {
    __shared__ int partial[256];
    int tid = threadIdx.x;
    int chunk = (n + 255) / 256;
    int begin = tid * chunk;
    int end = begin + chunk < n ? begin + chunk : n;
    int s = 0;
    for (int j = begin; j < end; ++j) s += counts[j];
    partial[tid] = s;
    __syncthreads();
    for (int off = 1; off < 256; off <<= 1) {
        int add = (tid >= off) ? partial[tid - off] : 0;
        int v = partial[tid];
        __syncthreads();
        partial[tid] = v + add;
        __syncthreads();
    }
    int run = (tid > 0) ? partial[tid - 1] : 0;
    for (int j = begin; j < end; ++j) {
        offsets[j] = run;
        cursor[j] = run;
        run += counts[j];
    }
    if (tid == 0) offsets[n] = partial[255];
}

__global__ void scatter_kernel(
    const int* __restrict__ src_idx, const int* __restrict__ dst_idx,
    const float* __restrict__ ew, int E, int* __restrict__ cursor,
    int* __restrict__ src_sorted, float* __restrict__ ew_sorted) {
    int e = blockIdx.x * blockDim.x + threadIdx.x;
    if (e < E) {
        int d = dst_idx[e];
        int pos = atomicAdd(&cursor[d], 1);
        src_sorted[pos] = src_idx[e];
        ew_sorted[pos] = ew[e];
    }
}

// One block per dst node. tid: t=tid>>6, c=tid&63. Register accumulation over
// the node's edge list (no atomics), then fused LayerNorm + residual.
__global__ __launch_bounds__(256) void aggregate_kernel(
    const float* __restrict__ h_src, const float* __restrict__ h_dst_v,
    const float* __restrict__ h_base, const float* __restrict__ feat_dst,
    const float* __restrict__ weight_e,
    const int* __restrict__ offsets, const int* __restrict__ src_sorted,
    const float* __restrict__ ew_sorted,
    const float* __restrict__ gamma, const float* __restrict__ beta,
    float* __restrict__ out) {
    int tid = threadIdx.x;
    int d = blockIdx.x;
    int t = tid >> 6;
    int c = tid & 63;
    size_t row = ((size_t)d * 4 + t) * 64 + c;

    float wec = weight_e[c];
    float hd  = h_dst_v[row];
    float acc = h_base[row];

    int e0 = offsets[d], e1 = offsets[d + 1];
    if (e0 < e1) {
        // software pipeline: prefetch next edge's gather while computing current
        int   s  = src_sorted[e0];
        float w  = ew_sorted[e0];
        float hs = h_src[((size_t)s * 4 + t) * 64 + c];
        for (int e = e0; e < e1; ++e) {
            float hs_c = hs, w_c = w;
            if (e + 1 < e1) {
                s  = src_sorted[e + 1];
                w  = ew_sorted[e + 1];
                hs = h_src[((size_t)s * 4 + t) * 64 + c];
            }
            float x = hs_c * hd * (w_c * wec);
            float g = 1.f / (1.f + __expf(-x));
            acc += hs_c * g;
        }
    }

    // LayerNorm over C=64 (one wave) + residual
    float s1 = acc, s2 = acc * acc;
#pragma unroll
    for (int off = 32; off >= 1; off >>= 1) {
        s1 += __shfl_xor(s1, off, 64);
        s2 += __shfl_xor(s2, off, 64);
    }
    float mean = s1 * (1.f / 64.f);
    float var  = s2 * (1.f / 64.f) - mean * mean;
    float inv  = rsqrtf(var + 1e-5f);
    out[row] = (acc - mean) * inv * gamma[c] + beta[c] + feat_dst[row];
}

extern "C" void kernel_launch(void* const* d_in, const int* in_sizes, int n_in,
                              void* d_out, int out_size, void* d_ws, size_t ws_size,
                              hipStream_t stream) {
    const float* feat_src    = (const float*)d_in[0];
    const float* feat_dst    = (const float*)d_in[1];
    const float* edge_weight = (const float*)d_in[2];
    const float* weight_e    = (const float*)d_in[3];
    const float* u           = (const float*)d_in[4];
    const float* v           = (const float*)d_in[5];
    const float* ln_gamma    = (const float*)d_in[6];
    const float* ln_beta     = (const float*)d_in[7];
    const int*   src_idx     = (const int*)d_in[8];
    const int*   dst_idx     = (const int*)d_in[9];
    float* out = (float*)d_out;

    int E          = in_sizes[2];
    int n_src_rows = in_sizes[0] / 64;          // N_SRC * T
    int n_dst_rows = in_sizes[1] / 64;          // N_DST * T
    int n_dst      = n_dst_rows / 4;            // T = 4

    // Workspace layout
    float* h_src     = (float*)d_ws;                            // N_SRC*T*C
    float* h_dst_v   = h_src + (size_t)n_src_rows * 64;         // N_DST*T*C
    float* h_base    = h_dst_v + (size_t)n_dst_rows * 64;       // N_DST*T*C
    float* ew_sorted = h_base + (size_t)n_dst_rows * 64;        // E
    int*   src_sorted= (int*)(ew_sorted + E);                   // E
    int*   counts    = src_sorted + E;                          // n_dst
    int*   offsets   = counts + n_dst;                          // n_dst+1
    int*   cursor    = offsets + n_dst + 1;                     // n_dst

    // 1) Projections
    proj_kernel<<<(n_src_rows + 3) / 4, 256, 0, stream>>>(feat_src, u, h_src, n_src_rows);
    proj_dual_kernel<<<(n_dst_rows + 3) / 4, 256, 0, stream>>>(feat_dst, u, v, h_base, h_dst_v, n_dst_rows);

    // 2) Counting sort of edges by destination
    zero_kernel<<<(n_dst + 255) / 256, 256, 0, stream>>>(counts, n_dst);
    hist_kernel<<<(E + 255) / 256, 256, 0, stream>>>(dst_idx, E, counts);
    scan_kernel<<<1, 256, 0, stream>>>(counts, n_dst, offsets, cursor);
    scatter_kernel<<<(E + 255) / 256, 256, 0, stream>>>(src_idx, dst_idx, edge_weight, E,
                                                        cursor, src_sorted, ew_sorted);

    // 3) Per-dst aggregation with fused LayerNorm + residual (no atomics)
    aggregate_kernel<<<n_dst, 256, 0, stream>>>(h_src, h_dst_v, h_base, feat_dst, weight_e,
                                                offsets, src_sorted, ew_sorted,
                                                ln_gamma, ln_beta, out);
}

// Round 3
// 188.907 us; speedup vs baseline: 2.2092x; 1.2885x over previous
//
#include <hip/hip_runtime.h>
#include <math.h>

// N_SRC=N_DST=10000, E=320000, T=4, C=64.
// Pipeline (5 launches):
//   proj_all  : h_srcT = (feat_src@u) transposed to [node][c][t] (+ sentinel row,
//               + zero counts); h_base = feat_dst@u, h_dst_v = feat_dst@v (std layout)
//   hist      : counts[d] = #edges into d
//   scan      : exclusive scan -> offsets, cursor
//   scatter   : counting-sort edges by dst (src_sorted, ew_sorted)
//   aggregate : per-dst register accumulation (float4/lane over t), fused sigmoid
//               gate + LayerNorm + residual. No atomics in the hot loop.

__global__ __launch_bounds__(256) void proj_all_kernel(
    const float* __restrict__ feat_src, const float* __restrict__ feat_dst,
    const float* __restrict__ U, const float* __restrict__ V,
    float* __restrict__ h_srcT, float* __restrict__ h_base, float* __restrict__ h_dst_v,
    int* __restrict__ counts, int n_src, int n_dst, int nsb) {
    __shared__ float sU[4096];
    __shared__ float sV[4096];
    int tid = threadIdx.x;
    int b = blockIdx.x;

    // zero counts (8 ints per block covers n_dst over the whole grid)
    if (tid < 8) {
        int zi = b * 8 + tid;
        if (zi < n_dst) counts[zi] = 0;
    }
    // sentinel row: h_srcT[n_src][*] = 0 (gathered by masked-out prefetch slots)
    if (b == 0) h_srcT[(size_t)n_src * 256 + tid] = 0.f;

    int w = tid >> 6, c = tid & 63;

    if (b < nsb) {
        // ---- src side: h_srcT[node][c][t] = (feat_src @ U)[node,t,c] ----
#pragma unroll
        for (int i = 0; i < 16; ++i) sU[tid + i * 256] = U[tid + i * 256];
        __syncthreads();
        int node0 = b * 16 + w * 4;   // wave handles 4 nodes
        for (int i = 0; i < 4; ++i) {
            int node = node0 + i;
#pragma unroll
            for (int t = 0; t < 4; ++t) {
                float a = feat_src[((size_t)node * 4 + t) * 64 + c];
                float acc = 0.f;
#pragma unroll
                for (int k = 0; k < 64; ++k)
                    acc += __shfl(a, k, 64) * sU[k * 64 + c];
                // transposed scatter store (16B stride; tiny volume, L2 merges)
                h_srcT[(size_t)node * 256 + c * 4 + t] = acc;
            }
        }
    } else {
        // ---- dst side: h_base = feat_dst@U, h_dst_v = feat_dst@V (std layout) ----
#pragma unroll
        for (int i = 0; i < 16; ++i) {
            sU[tid + i * 256] = U[tid + i * 256];
            sV[tid + i * 256] = V[tid + i * 256];
        }
        __syncthreads();
        int r0 = (b - nsb) * 64 + w * 16;   // wave handles 16 rows
        for (int i = 0; i < 16; ++i) {
            int r = r0 + i;
            float a = feat_dst[(size_t)r * 64 + c];
            float accU = 0.f, accV = 0.f;
#pragma unroll
            for (int k = 0; k < 64; ++k) {
                float bk = __shfl(a, k, 64);
                accU += bk * sU[k * 64 + c];
                accV += bk * sV[k * 64 + c];
            }
            h_base[(size_t)r * 64 + c] = accU;
            h_dst_v[(size_t)r * 64 + c] = accV;
        }
    }
}

__global__ void hist_kernel(const int* __restrict__ dst_idx, int E, int* __restrict__ counts) {
    int e = blockIdx.x * blockDim.x + threadIdx.x;
    if (e < E) atomicAdd(&counts[dst_idx[e]], 1);
}

__global__ __launch_bounds__(1024) void scan_kernel(
    const int* __restrict__ counts, int n,
    int* __restrict__ offsets, int* __restrict__ cursor) {
    __shared__ int partial[1024];
    int tid = threadIdx.x;
    int chunk = (n + 1023) >> 10;
    int begin = tid * chunk;
    int end = begin + chunk < n ? begin + chunk : n;
    int s = 0;
    for (int j = begin; j < end; ++j) s += counts[j];
    partial[tid] = s;
    __syncthreads();
    for (int off = 1; off < 1024; off <<= 1) {
        int add = (tid >= off) ? partial[tid - off] : 0;
        __syncthreads();
        partial[tid] += add;
        __syncthreads();
    }
    int run = (tid > 0) ? partial[tid - 1] : 0;
    for (int j = begin; j < end; ++j) {
        offsets[j] = run;
        cursor[j] = run;
        run += counts[j];
    }
    if (tid == 0) offsets[n] = partial[1023];
}

__global__ void scatter_kernel(
    const int* __restrict__ src_idx, const int* __restrict__ dst_idx,
    const float* __restrict__ ew, int E, int* __restrict__ cursor,
    int* __restrict__ src_sorted, float* __restrict__ ew_sorted) {
    int e = blockIdx.x * blockDim.x + threadIdx.x;
    if (e < E) {
        int d = dst_idx[e];
        int pos = atomicAdd(&cursor[d], 1);
        src_sorted[pos] = src_idx[e];
        ew_sorted[pos] = ew[e];
    }
}

// One wave per dst node; lane c holds float4 over t. Group-of-4 ping-pong prefetch.
__global__ __launch_bounds__(256) void aggregate_kernel(
    const float4* __restrict__ h_srcT,   // [(n_src+1)*64] float4s: node*64 + c
    const float* __restrict__ h_dst_v, const float* __restrict__ h_base,
    const float* __restrict__ feat_dst, const float* __restrict__ weight_e,
    const int* __restrict__ offsets, const int* __restrict__ src_sorted,
    const float* __restrict__ ew_sorted,
    const float* __restrict__ gamma, const float* __restrict__ beta,
    float* __restrict__ out, int n_src) {
    int tid = threadIdx.x;
    int w = tid >> 6, c = tid & 63;
    int d = blockIdx.x * 4 + w;
    size_t rb = (size_t)d * 256;

    float wec = weight_e[c];
    // acc over t; coefficient hw_t = hd_t * wec * (-log2 e)  (so exp2(hs*hw*w) = exp(-x))
    float acc0 = h_base[rb +   0 + c], acc1 = h_base[rb +  64 + c];
    float acc2 = h_base[rb + 128 + c], acc3 = h_base[rb + 192 + c];
    const float nl2e = -1.44269504f;
    float hw0 = h_dst_v[rb +   0 + c] * wec * nl2e;
    float hw1 = h_dst_v[rb +  64 + c] * wec * nl2e;
    float hw2 = h_dst_v[rb + 128 + c] * wec * nl2e;
    float hw3 = h_dst_v[rb + 192 + c] * wec * nl2e;

    int e0 = offsets[d], e1 = offsets[d + 1];

    float4 hA[4]; float wA[4];
#pragma unroll
    for (int i = 0; i < 4; ++i) {
        int ee = e0 + i;
        bool ok = ee < e1;
        int s = ok ? src_sorted[ee] : n_src;      // sentinel row = zeros
        wA[i] = ok ? ew_sorted[ee] : 0.f;
        hA[i] = h_srcT[(size_t)s * 64 + c];
    }

    for (int base = e0; base < e1; base += 4) {
        float4 hB[4]; float wB[4];
#pragma unroll
        for (int i = 0; i < 4; ++i) {
            int ee = base + 4 + i;
            bool ok = ee < e1;
            int s = ok ? src_sorted[ee] : n_src;
            wB[i] = ok ? ew_sorted[ee] : 0.f;
            hB[i] = h_srcT[(size_t)s * 64 + c];
        }
#pragma unroll
        for (int i = 0; i < 4; ++i) {
            float ww = wA[i];
            float4 hs = hA[i];
            float g0 = __builtin_amdgcn_rcpf(1.f + __builtin_amdgcn_exp2f(hs.x * (hw0 * ww)));
            float g1 = __builtin_amdgcn_rcpf(1.f + __builtin_amdgcn_exp2f(hs.y * (hw1 * ww)));
            float g2 = __builtin_amdgcn_rcpf(1.f + __builtin_amdgcn_exp2f(hs.z * (hw2 * ww)));
            float g3 = __builtin_amdgcn_rcpf(1.f + __builtin_amdgcn_exp2f(hs.w * (hw3 * ww)));
            acc0 = fmaf(hs.x, g0, acc0);
            acc1 = fmaf(hs.y, g1, acc1);
            acc2 = fmaf(hs.z, g2, acc2);
            acc3 = fmaf(hs.w, g3, acc3);
        }
#pragma unroll
        for (int i = 0; i < 4; ++i) { hA[i] = hB[i]; wA[i] = wB[i]; }
    }

    // fused LayerNorm (over c = lanes, per t) + residual
    float s10 = acc0, s11 = acc1, s12 = acc2, s13 = acc3;
    float s20 = acc0 * acc0, s21 = acc1 * acc1, s22 = acc2 * acc2, s23 = acc3 * acc3;
#pragma unroll
    for (int off = 32; off >= 1; off >>= 1) {
        s10 += __shfl_xor(s10, off, 64); s20 += __shfl_xor(s20, off, 64);
        s11 += __shfl_xor(s11, off, 64); s21 += __shfl_xor(s21, off, 64);
        s12 += __shfl_xor(s12, off, 64); s22 += __shfl_xor(s22, off, 64);
        s13 += __shfl_xor(s13, off, 64); s23 += __shfl_xor(s23, off, 64);
    }
    float gm = gamma[c], bt = beta[c];
    const float inv64 = 1.f / 64.f;
#pragma unroll
    for (int t = 0; t < 4; ++t) {
        float acc = t == 0 ? acc0 : t == 1 ? acc1 : t == 2 ? acc2 : acc3;
        float s1  = t == 0 ? s10  : t == 1 ? s11  : t == 2 ? s12  : s13;
        float s2  = t == 0 ? s20  : t == 1 ? s21  : t == 2 ? s22  : s23;
        float mean = s1 * inv64;
        float var  = s2 * inv64 - mean * mean;
        float inv  = rsqrtf(var + 1e-5f);
        out[rb + t * 64 + c] = (acc - mean) * inv * gm + bt + feat_dst[rb + t * 64 + c];
    }
}

extern "C" void kernel_launch(void* const* d_in, const int* in_sizes, int n_in,
                              void* d_out, int out_size, void* d_ws, size_t ws_size,
                              hipStream_t stream) {
    const float* feat_src    = (const float*)d_in[0];
    const float* feat_dst    = (const float*)d_in[1];
    const float* edge_weight = (const float*)d_in[2];
    const float* weight_e    = (const float*)d_in[3];
    const float* u           = (const float*)d_in[4];
    const float* v           = (const float*)d_in[5];
    const float* ln_gamma    = (const float*)d_in[6];
    const float* ln_beta     = (const float*)d_in[7];
    const int*   src_idx     = (const int*)d_in[8];
    const int*   dst_idx     = (const int*)d_in[9];
    float* out = (float*)d_out;

    int E     = in_sizes[2];
    int n_src = in_sizes[0] / 256;   // N_SRC (T*C = 256)
    int n_dst = in_sizes[1] / 256;   // N_DST

    // Workspace layout
    float* h_srcT    = (float*)d_ws;                            // (n_src+1)*256
    float* h_base    = h_srcT + (size_t)(n_src + 1) * 256;      // n_dst*256
    float* h_dst_v   = h_base + (size_t)n_dst * 256;            // n_dst*256
    float* ew_sorted = h_dst_v + (size_t)n_dst * 256;           // E
    int*   src_sorted= (int*)(ew_sorted + E);                   // E
    int*   counts    = src_sorted + E;                          // n_dst
    int*   offsets   = counts + n_dst;                          // n_dst+1
    int*   cursor    = offsets + n_dst + 1;                     // n_dst

    int nsb = n_src / 16;            // src blocks (16 nodes each)
    int ndb = n_dst / 16;

    proj_all_kernel<<<nsb + ndb, 256, 0, stream>>>(feat_src, feat_dst, u, v,
                                                   h_srcT, h_base, h_dst_v,
                                                   counts, n_src, n_dst, nsb);
    hist_kernel<<<(E + 255) / 256, 256, 0, stream>>>(dst_idx, E, counts);
    scan_kernel<<<1, 1024, 0, stream>>>(counts, n_dst, offsets, cursor);
    scatter_kernel<<<(E + 255) / 256, 256, 0, stream>>>(src_idx, dst_idx, edge_weight, E,
                                                        cursor, src_sorted, ew_sorted);
    aggregate_kernel<<<n_dst / 4, 256, 0, stream>>>((const float4*)h_srcT, h_dst_v, h_base,
                                                    feat_dst, weight_e,
                                                    offsets, src_sorted, ew_sorted,
                                                    ln_gamma, ln_beta, out, n_src);
}

// Round 4
// 167.049 us; speedup vs baseline: 2.4983x; 1.1308x over previous
//
#include <hip/hip_runtime.h>
#include <math.h>

// N_SRC=N_DST=10000, E=320000, T=4, C=64.
// Pipeline (5 launches):
//   proj_all  : 3 GEMV paths, one wave per node:
//               path0: h_srcT = (feat_src@u) stored transposed [node][c][t] (+ zero sentinel row)
//               path1: h_base = feat_dst@u   path2: h_dst_v = feat_dst@v
//               (+ zero counts). Broadcast-GEMV: A-row via wave-uniform float4 loads,
//               W column from LDS, 4 independent acc chains (t=0..3).
//   hist      : counts[d] = #edges into d
//   scan      : exclusive scan -> offsets, cursor
//   scatter   : counting-sort edges by dst (src_sorted, ew_sorted)
//   aggregate : per-dst register accumulation (float4/lane over t), fused sigmoid
//               gate + LayerNorm + residual. No atomics in the hot loop.

__global__ __launch_bounds__(256) void proj_all_kernel(
    const float* __restrict__ feat_src, const float* __restrict__ feat_dst,
    const float* __restrict__ U, const float* __restrict__ V,
    float* __restrict__ h_srcT, float* __restrict__ h_base, float* __restrict__ h_dst_v,
    int* __restrict__ counts, int n_src, int n_dst) {
    __shared__ float sW[4096];
    int tid = threadIdx.x;
    int b   = blockIdx.x;
    int nb_src = (n_src + 3) >> 2;   // 4 nodes per block (1 per wave)
    int nb_dst = (n_dst + 3) >> 2;

    // distributed once-per-call init (before the barrier)
    if (tid < 2) {
        int zi = b * 2 + tid;
        if (zi < n_dst) counts[zi] = 0;
    }
    if (b == 0) h_srcT[(size_t)n_src * 256 + tid] = 0.f;   // sentinel row = zeros

    const float* W;
    const float* feat;
    int nidx, path, nmax;
    if (b < nb_src)               { path = 0; W = U; feat = feat_src; nidx = b;                   nmax = n_src; }
    else if (b < nb_src + nb_dst) { path = 1; W = U; feat = feat_dst; nidx = b - nb_src;          nmax = n_dst; }
    else                          { path = 2; W = V; feat = feat_dst; nidx = b - nb_src - nb_dst; nmax = n_dst; }

    // stage this path's W into LDS, linear [k][c] (lane c -> stride-1 across lanes: conflict-free)
#pragma unroll
    for (int i = 0; i < 16; ++i) sW[tid + i * 256] = W[tid + i * 256];
    __syncthreads();

    int w = tid >> 6, c = tid & 63;
    int node = nidx * 4 + w;
    if (node >= nmax) node = nmax - 1;   // clamp instead of early return (barrier safety)

    const float4* A = (const float4*)(feat + (size_t)node * 256);   // 4 rows x 16 float4

    float  acc[4] = {0.f, 0.f, 0.f, 0.f};
    float4 ab[3][4];   // A prefetch ring, depth 3 (all indices static after unroll)
    float  wb[2][4];   // W chunk ping-pong

#pragma unroll
    for (int t = 0; t < 4; ++t) ab[0][t] = A[t * 16 + 0];
#pragma unroll
    for (int t = 0; t < 4; ++t) ab[1][t] = A[t * 16 + 1];
#pragma unroll
    for (int e = 0; e < 4; ++e) wb[0][e] = sW[e * 64 + c];

#pragma unroll
    for (int kc = 0; kc < 16; ++kc) {
        if (kc < 14) {
#pragma unroll
            for (int t = 0; t < 4; ++t) ab[(kc + 2) % 3][t] = A[t * 16 + kc + 2];
        }
        if (kc < 15) {
#pragma unroll
            for (int e = 0; e < 4; ++e) wb[(kc + 1) & 1][e] = sW[(4 * (kc + 1) + e) * 64 + c];
        }
#pragma unroll
        for (int t = 0; t < 4; ++t) {
            acc[t] = fmaf(ab[kc % 3][t].x, wb[kc & 1][0], acc[t]);
            acc[t] = fmaf(ab[kc % 3][t].y, wb[kc & 1][1], acc[t]);
            acc[t] = fmaf(ab[kc % 3][t].z, wb[kc & 1][2], acc[t]);
            acc[t] = fmaf(ab[kc % 3][t].w, wb[kc & 1][3], acc[t]);
        }
    }

    if (path == 0) {
        // transposed store: lane c holds exactly h_srcT[node][c][0..3] -> coalesced float4
        float4 st; st.x = acc[0]; st.y = acc[1]; st.z = acc[2]; st.w = acc[3];
        ((float4*)h_srcT)[(size_t)node * 64 + c] = st;
    } else {
        float* o = (path == 1 ? h_base : h_dst_v) + (size_t)node * 256 + c;
        o[0] = acc[0]; o[64] = acc[1]; o[128] = acc[2]; o[192] = acc[3];
    }
}

__global__ void hist_kernel(const int* __restrict__ dst_idx, int E, int* __restrict__ counts) {
    int e = blockIdx.x * blockDim.x + threadIdx.x;
    if (e < E) atomicAdd(&counts[dst_idx[e]], 1);
}

__global__ __launch_bounds__(1024) void scan_kernel(
    const int* __restrict__ counts, int n,
    int* __restrict__ offsets, int* __restrict__ cursor) {
    __shared__ int partial[1024];
    int tid = threadIdx.x;
    int chunk = (n + 1023) >> 10;
    int begin = tid * chunk;
    int end = begin + chunk < n ? begin + chunk : n;
    int s = 0;
    for (int j = begin; j < end; ++j) s += counts[j];
    partial[tid] = s;
    __syncthreads();
    for (int off = 1; off < 1024; off <<= 1) {
        int add = (tid >= off) ? partial[tid - off] : 0;
        __syncthreads();
        partial[tid] += add;
        __syncthreads();
    }
    int run = (tid > 0) ? partial[tid - 1] : 0;
    for (int j = begin; j < end; ++j) {
        offsets[j] = run;
        cursor[j] = run;
        run += counts[j];
    }
    if (tid == 0) offsets[n] = partial[1023];
}

__global__ void scatter_kernel(
    const int* __restrict__ src_idx, const int* __restrict__ dst_idx,
    const float* __restrict__ ew, int E, int* __restrict__ cursor,
    int* __restrict__ src_sorted, float* __restrict__ ew_sorted) {
    int e = blockIdx.x * blockDim.x + threadIdx.x;
    if (e < E) {
        int d = dst_idx[e];
        int pos = atomicAdd(&cursor[d], 1);
        src_sorted[pos] = src_idx[e];
        ew_sorted[pos] = ew[e];
    }
}

// One wave per dst node; lane c holds float4 over t. Group-of-4 ping-pong prefetch.
__global__ __launch_bounds__(256) void aggregate_kernel(
    const float4* __restrict__ h_srcT,   // [(n_src+1)*64] float4s: node*64 + c
    const float* __restrict__ h_dst_v, const float* __restrict__ h_base,
    const float* __restrict__ feat_dst, const float* __restrict__ weight_e,
    const int* __restrict__ offsets, const int* __restrict__ src_sorted,
    const float* __restrict__ ew_sorted,
    const float* __restrict__ gamma, const float* __restrict__ beta,
    float* __restrict__ out, int n_src) {
    int tid = threadIdx.x;
    int w = tid >> 6, c = tid & 63;
    int d = blockIdx.x * 4 + w;
    size_t rb = (size_t)d * 256;

    float wec = weight_e[c];
    float acc0 = h_base[rb +   0 + c], acc1 = h_base[rb +  64 + c];
    float acc2 = h_base[rb + 128 + c], acc3 = h_base[rb + 192 + c];
    const float nl2e = -1.44269504f;
    float hw0 = h_dst_v[rb +   0 + c] * wec * nl2e;
    float hw1 = h_dst_v[rb +  64 + c] * wec * nl2e;
    float hw2 = h_dst_v[rb + 128 + c] * wec * nl2e;
    float hw3 = h_dst_v[rb + 192 + c] * wec * nl2e;

    int e0 = offsets[d], e1 = offsets[d + 1];

    float4 hA[4]; float wA[4];
#pragma unroll
    for (int i = 0; i < 4; ++i) {
        int ee = e0 + i;
        bool ok = ee < e1;
        int s = ok ? src_sorted[ee] : n_src;      // sentinel row = zeros
        wA[i] = ok ? ew_sorted[ee] : 0.f;
        hA[i] = h_srcT[(size_t)s * 64 + c];
    }

    for (int base = e0; base < e1; base += 4) {
        float4 hB[4]; float wB[4];
#pragma unroll
        for (int i = 0; i < 4; ++i) {
            int ee = base + 4 + i;
            bool ok = ee < e1;
            int s = ok ? src_sorted[ee] : n_src;
            wB[i] = ok ? ew_sorted[ee] : 0.f;
            hB[i] = h_srcT[(size_t)s * 64 + c];
        }
#pragma unroll
        for (int i = 0; i < 4; ++i) {
            float ww = wA[i];
            float4 hs = hA[i];
            float g0 = __builtin_amdgcn_rcpf(1.f + __builtin_amdgcn_exp2f(hs.x * (hw0 * ww)));
            float g1 = __builtin_amdgcn_rcpf(1.f + __builtin_amdgcn_exp2f(hs.y * (hw1 * ww)));
            float g2 = __builtin_amdgcn_rcpf(1.f + __builtin_amdgcn_exp2f(hs.z * (hw2 * ww)));
            float g3 = __builtin_amdgcn_rcpf(1.f + __builtin_amdgcn_exp2f(hs.w * (hw3 * ww)));
            acc0 = fmaf(hs.x, g0, acc0);
            acc1 = fmaf(hs.y, g1, acc1);
            acc2 = fmaf(hs.z, g2, acc2);
            acc3 = fmaf(hs.w, g3, acc3);
        }
#pragma unroll
        for (int i = 0; i < 4; ++i) { hA[i] = hB[i]; wA[i] = wB[i]; }
    }

    // fused LayerNorm (over c = lanes, per t) + residual
    float s10 = acc0, s11 = acc1, s12 = acc2, s13 = acc3;
    float s20 = acc0 * acc0, s21 = acc1 * acc1, s22 = acc2 * acc2, s23 = acc3 * acc3;
#pragma unroll
    for (int off = 32; off >= 1; off >>= 1) {
        s10 += __shfl_xor(s10, off, 64); s20 += __shfl_xor(s20, off, 64);
        s11 += __shfl_xor(s11, off, 64); s21 += __shfl_xor(s21, off, 64);
        s12 += __shfl_xor(s12, off, 64); s22 += __shfl_xor(s22, off, 64);
        s13 += __shfl_xor(s13, off, 64); s23 += __shfl_xor(s23, off, 64);
    }
    float gm = gamma[c], bt = beta[c];
    const float inv64 = 1.f / 64.f;
#pragma unroll
    for (int t = 0; t < 4; ++t) {
        float acc = t == 0 ? acc0 : t == 1 ? acc1 : t == 2 ? acc2 : acc3;
        float s1  = t == 0 ? s10  : t == 1 ? s11  : t == 2 ? s12  : s13;
        float s2  = t == 0 ? s20  : t == 1 ? s21  : t == 2 ? s22  : s23;
        float mean = s1 * inv64;
        float var  = s2 * inv64 - mean * mean;
        float inv  = rsqrtf(var + 1e-5f);
        out[rb + t * 64 + c] = (acc - mean) * inv * gm + bt + feat_dst[rb + t * 64 + c];
    }
}

extern "C" void kernel_launch(void* const* d_in, const int* in_sizes, int n_in,
                              void* d_out, int out_size, void* d_ws, size_t ws_size,
                              hipStream_t stream) {
    const float* feat_src    = (const float*)d_in[0];
    const float* feat_dst    = (const float*)d_in[1];
    const float* edge_weight = (const float*)d_in[2];
    const float* weight_e    = (const float*)d_in[3];
    const float* u           = (const float*)d_in[4];
    const float* v           = (const float*)d_in[5];
    const float* ln_gamma    = (const float*)d_in[6];
    const float* ln_beta     = (const float*)d_in[7];
    const int*   src_idx     = (const int*)d_in[8];
    const int*   dst_idx     = (const int*)d_in[9];
    float* out = (float*)d_out;

    int E     = in_sizes[2];
    int n_src = in_sizes[0] / 256;   // N_SRC (T*C = 256)
    int n_dst = in_sizes[1] / 256;   // N_DST

    // Workspace layout
    float* h_srcT    = (float*)d_ws;                            // (n_src+1)*256
    float* h_base    = h_srcT + (size_t)(n_src + 1) * 256;      // n_dst*256
    float* h_dst_v   = h_base + (size_t)n_dst * 256;            // n_dst*256
    float* ew_sorted = h_dst_v + (size_t)n_dst * 256;           // E
    int*   src_sorted= (int*)(ew_sorted + E);                   // E
    int*   counts    = src_sorted + E;                          // n_dst
    int*   offsets   = counts + n_dst;                          // n_dst+1
    int*   cursor    = offsets + n_dst + 1;                     // n_dst

    int nb_src = (n_src + 3) / 4;
    int nb_dst = (n_dst + 3) / 4;

    proj_all_kernel<<<nb_src + 2 * nb_dst, 256, 0, stream>>>(feat_src, feat_dst, u, v,
                                                             h_srcT, h_base, h_dst_v,
                                                             counts, n_src, n_dst);
    hist_kernel<<<(E + 255) / 256, 256, 0, stream>>>(dst_idx, E, counts);
    scan_kernel<<<1, 1024, 0, stream>>>(counts, n_dst, offsets, cursor);
    scatter_kernel<<<(E + 255) / 256, 256, 0, stream>>>(src_idx, dst_idx, edge_weight, E,
                                                        cursor, src_sorted, ew_sorted);
    aggregate_kernel<<<n_dst / 4, 256, 0, stream>>>((const float4*)h_srcT, h_dst_v, h_base,
                                                    feat_dst, weight_e,
                                                    offsets, src_sorted, ew_sorted,
                                                    ln_gamma, ln_beta, out, n_src);
}

// Round 5
// 124.765 us; speedup vs baseline: 3.3450x; 1.3389x over previous
//
#include <hip/hip_runtime.h>
#include <math.h>

// N_SRC=N_DST=10000, E=320000, T=4, C=64.
// Pipeline (5 launches):
//   proj_kernel : LDS-tiled fp32 GEMM, 64x64 tile per block, thread = 4x4 micro-tile.
//     src blocks: h_srcT = (feat_src@u) stored transposed [node][c][t] (+ sentinel row)
//     dst blocks: h_base = feat_dst@u AND h_dst_v = feat_dst@v from one staged A-tile
//     (+ distributed zeroing of counts)
//   hist | scan | scatter : counting sort of edges by dst
//   aggregate : per-dst register accumulation (float4/lane over t), fused sigmoid
//               gate + LayerNorm + residual. No atomics in the hot loop.

__global__ __launch_bounds__(256) void proj_kernel(
    const float* __restrict__ feat_src, const float* __restrict__ feat_dst,
    const float* __restrict__ U, const float* __restrict__ V,
    float* __restrict__ h_srcT, float* __restrict__ h_base, float* __restrict__ h_dst_v,
    int* __restrict__ counts, int n_src, int n_dst) {
    __shared__ float sA[64 * 68];   // A-tile [64 rows][64 k], stride 68 (2-bank alias = free)
    __shared__ float sU[4096];      // U [k][c]
    __shared__ float sV[4096];      // V [k][c] (dst path only)
    int t = threadIdx.x, b = blockIdx.x;
    int nsb = (n_src * 4 + 63) >> 6;

    // distributed once-per-call init
    for (int zi = b * 8 + t; t < 8 && zi < n_dst; zi += gridDim.x * 8) counts[zi] = 0;
    if (b == 0) h_srcT[(size_t)n_src * 256 + t] = 0.f;   // sentinel row = zeros

    bool is_src = b < nsb;
    int rb = is_src ? b : b - nsb;
    int nrows = (is_src ? n_src : n_dst) * 4;
    int r0 = rb * 64;
    const float* A = is_src ? feat_src : feat_dst;

    // ---- stage W (and V for dst path) ----
    {
        const float4* U4 = (const float4*)U;
        float4* sU4 = (float4*)sU;
#pragma unroll
        for (int i = 0; i < 4; ++i) sU4[t + i * 256] = U4[t + i * 256];
        if (!is_src) {
            const float4* V4 = (const float4*)V;
            float4* sV4 = (float4*)sV;
#pragma unroll
            for (int i = 0; i < 4; ++i) sV4[t + i * 256] = V4[t + i * 256];
        }
    }
    // ---- stage A tile, coalesced (wave covers 4 rows x 256B contiguous) ----
    {
        int row = t >> 4, chunk = t & 15;
#pragma unroll
        for (int p = 0; p < 4; ++p) {
            int rr = row + p * 16;
            int r = r0 + rr;
            if (r >= nrows) r = nrows - 1;
            float4 v = *(const float4*)(A + (size_t)r * 64 + chunk * 4);
            *(float4*)&sA[rr * 68 + chunk * 4] = v;
        }
    }
    __syncthreads();

    int rg = t >> 4;            // row group: rows rg*4 .. rg*4+3
    int c4 = (t & 15) * 4;      // cols c4 .. c4+3

    if (is_src) {
        float acc[4][4];
#pragma unroll
        for (int j = 0; j < 4; ++j)
#pragma unroll
            for (int m = 0; m < 4; ++m) acc[j][m] = 0.f;
#pragma unroll 16
        for (int k = 0; k < 64; ++k) {
            float4 wu = *(const float4*)&sU[k * 64 + c4];
#pragma unroll
            for (int j = 0; j < 4; ++j) {
                float a = sA[(rg * 4 + j) * 68 + k];
                acc[j][0] = fmaf(a, wu.x, acc[j][0]);
                acc[j][1] = fmaf(a, wu.y, acc[j][1]);
                acc[j][2] = fmaf(a, wu.z, acc[j][2]);
                acc[j][3] = fmaf(a, wu.w, acc[j][3]);
            }
        }
        // rows rg*4..rg*4+3 are (node, t=0..3); store transposed: h_srcT[node][c][t]
        int node = (r0 >> 2) + rg;
        if (node < n_src) {
#pragma unroll
            for (int m = 0; m < 4; ++m) {
                float4 st;
                st.x = acc[0][m]; st.y = acc[1][m]; st.z = acc[2][m]; st.w = acc[3][m];
                *(float4*)&h_srcT[(size_t)node * 256 + (size_t)(c4 + m) * 4] = st;
            }
        }
    } else {
        float accU[4][4], accV[4][4];
#pragma unroll
        for (int j = 0; j < 4; ++j)
#pragma unroll
            for (int m = 0; m < 4; ++m) { accU[j][m] = 0.f; accV[j][m] = 0.f; }
#pragma unroll 8
        for (int k = 0; k < 64; ++k) {
            float4 wu = *(const float4*)&sU[k * 64 + c4];
            float4 wv = *(const float4*)&sV[k * 64 + c4];
#pragma unroll
            for (int j = 0; j < 4; ++j) {
                float a = sA[(rg * 4 + j) * 68 + k];
                accU[j][0] = fmaf(a, wu.x, accU[j][0]);
                accU[j][1] = fmaf(a, wu.y, accU[j][1]);
                accU[j][2] = fmaf(a, wu.z, accU[j][2]);
                accU[j][3] = fmaf(a, wu.w, accU[j][3]);
                accV[j][0] = fmaf(a, wv.x, accV[j][0]);
                accV[j][1] = fmaf(a, wv.y, accV[j][1]);
                accV[j][2] = fmaf(a, wv.z, accV[j][2]);
                accV[j][3] = fmaf(a, wv.w, accV[j][3]);
            }
        }
#pragma unroll
        for (int j = 0; j < 4; ++j) {
            int r = r0 + rg * 4 + j;
            if (r < nrows) {
                float4 su, sv;
                su.x = accU[j][0]; su.y = accU[j][1]; su.z = accU[j][2]; su.w = accU[j][3];
                sv.x = accV[j][0]; sv.y = accV[j][1]; sv.z = accV[j][2]; sv.w = accV[j][3];
                *(float4*)&h_base [(size_t)r * 64 + c4] = su;
                *(float4*)&h_dst_v[(size_t)r * 64 + c4] = sv;
            }
        }
    }
}

__global__ void hist_kernel(const int* __restrict__ dst_idx, int E, int* __restrict__ counts) {
    int e = blockIdx.x * blockDim.x + threadIdx.x;
    if (e < E) atomicAdd(&counts[dst_idx[e]], 1);
}

__global__ __launch_bounds__(1024) void scan_kernel(
    const int* __restrict__ counts, int n,
    int* __restrict__ offsets, int* __restrict__ cursor) {
    __shared__ int partial[1024];
    int tid = threadIdx.x;
    int chunk = (n + 1023) >> 10;
    int begin = tid * chunk;
    int end = begin + chunk < n ? begin + chunk : n;
    int s = 0;
    for (int j = begin; j < end; ++j) s += counts[j];
    partial[tid] = s;
    __syncthreads();
    for (int off = 1; off < 1024; off <<= 1) {
        int add = (tid >= off) ? partial[tid - off] : 0;
        __syncthreads();
        partial[tid] += add;
        __syncthreads();
    }
    int run = (tid > 0) ? partial[tid - 1] : 0;
    for (int j = begin; j < end; ++j) {
        offsets[j] = run;
        cursor[j] = run;
        run += counts[j];
    }
    if (tid == 0) offsets[n] = partial[1023];
}

__global__ void scatter_kernel(
    const int* __restrict__ src_idx, const int* __restrict__ dst_idx,
    const float* __restrict__ ew, int E, int* __restrict__ cursor,
    int* __restrict__ src_sorted, float* __restrict__ ew_sorted) {
    int e = blockIdx.x * blockDim.x + threadIdx.x;
    if (e < E) {
        int d = dst_idx[e];
        int pos = atomicAdd(&cursor[d], 1);
        src_sorted[pos] = src_idx[e];
        ew_sorted[pos] = ew[e];
    }
}

// One wave per dst node; lane c holds float4 over t. Group-of-4 ping-pong prefetch.
__global__ __launch_bounds__(256) void aggregate_kernel(
    const float4* __restrict__ h_srcT,   // [(n_src+1)*64] float4s: node*64 + c
    const float* __restrict__ h_dst_v, const float* __restrict__ h_base,
    const float* __restrict__ feat_dst, const float* __restrict__ weight_e,
    const int* __restrict__ offsets, const int* __restrict__ src_sorted,
    const float* __restrict__ ew_sorted,
    const float* __restrict__ gamma, const float* __restrict__ beta,
    float* __restrict__ out, int n_src) {
    int tid = threadIdx.x;
    int w = tid >> 6, c = tid & 63;
    int d = blockIdx.x * 4 + w;
    size_t rb = (size_t)d * 256;

    float wec = weight_e[c];
    float acc0 = h_base[rb +   0 + c], acc1 = h_base[rb +  64 + c];
    float acc2 = h_base[rb + 128 + c], acc3 = h_base[rb + 192 + c];
    const float nl2e = -1.44269504f;
    float hw0 = h_dst_v[rb +   0 + c] * wec * nl2e;
    float hw1 = h_dst_v[rb +  64 + c] * wec * nl2e;
    float hw2 = h_dst_v[rb + 128 + c] * wec * nl2e;
    float hw3 = h_dst_v[rb + 192 + c] * wec * nl2e;

    int e0 = offsets[d], e1 = offsets[d + 1];

    float4 hA[4]; float wA[4];
#pragma unroll
    for (int i = 0; i < 4; ++i) {
        int ee = e0 + i;
        bool ok = ee < e1;
        int s = ok ? src_sorted[ee] : n_src;      // sentinel row = zeros
        wA[i] = ok ? ew_sorted[ee] : 0.f;
        hA[i] = h_srcT[(size_t)s * 64 + c];
    }

    for (int base = e0; base < e1; base += 4) {
        float4 hB[4]; float wB[4];
#pragma unroll
        for (int i = 0; i < 4; ++i) {
            int ee = base + 4 + i;
            bool ok = ee < e1;
            int s = ok ? src_sorted[ee] : n_src;
            wB[i] = ok ? ew_sorted[ee] : 0.f;
            hB[i] = h_srcT[(size_t)s * 64 + c];
        }
#pragma unroll
        for (int i = 0; i < 4; ++i) {
            float ww = wA[i];
            float4 hs = hA[i];
            float g0 = __builtin_amdgcn_rcpf(1.f + __builtin_amdgcn_exp2f(hs.x * (hw0 * ww)));
            float g1 = __builtin_amdgcn_rcpf(1.f + __builtin_amdgcn_exp2f(hs.y * (hw1 * ww)));
            float g2 = __builtin_amdgcn_rcpf(1.f + __builtin_amdgcn_exp2f(hs.z * (hw2 * ww)));
            float g3 = __builtin_amdgcn_rcpf(1.f + __builtin_amdgcn_exp2f(hs.w * (hw3 * ww)));
            acc0 = fmaf(hs.x, g0, acc0);
            acc1 = fmaf(hs.y, g1, acc1);
            acc2 = fmaf(hs.z, g2, acc2);
            acc3 = fmaf(hs.w, g3, acc3);
        }
#pragma unroll
        for (int i = 0; i < 4; ++i) { hA[i] = hB[i]; wA[i] = wB[i]; }
    }

    // fused LayerNorm (over c = lanes, per t) + residual
    float s10 = acc0, s11 = acc1, s12 = acc2, s13 = acc3;
    float s20 = acc0 * acc0, s21 = acc1 * acc1, s22 = acc2 * acc2, s23 = acc3 * acc3;
#pragma unroll
    for (int off = 32; off >= 1; off >>= 1) {
        s10 += __shfl_xor(s10, off, 64); s20 += __shfl_xor(s20, off, 64);
        s11 += __shfl_xor(s11, off, 64); s21 += __shfl_xor(s21, off, 64);
        s12 += __shfl_xor(s12, off, 64); s22 += __shfl_xor(s22, off, 64);
        s13 += __shfl_xor(s13, off, 64); s23 += __shfl_xor(s23, off, 64);
    }
    float gm = gamma[c], bt = beta[c];
    const float inv64 = 1.f / 64.f;
#pragma unroll
    for (int t = 0; t < 4; ++t) {
        float acc = t == 0 ? acc0 : t == 1 ? acc1 : t == 2 ? acc2 : acc3;
        float s1  = t == 0 ? s10  : t == 1 ? s11  : t == 2 ? s12  : s13;
        float s2  = t == 0 ? s20  : t == 1 ? s21  : t == 2 ? s22  : s23;
        float mean = s1 * inv64;
        float var  = s2 * inv64 - mean * mean;
        float inv  = rsqrtf(var + 1e-5f);
        out[rb + t * 64 + c] = (acc - mean) * inv * gm + bt + feat_dst[rb + t * 64 + c];
    }
}

extern "C" void kernel_launch(void* const* d_in, const int* in_sizes, int n_in,
                              void* d_out, int out_size, void* d_ws, size_t ws_size,
                              hipStream_t stream) {
    const float* feat_src    = (const float*)d_in[0];
    const float* feat_dst    = (const float*)d_in[1];
    const float* edge_weight = (const float*)d_in[2];
    const float* weight_e    = (const float*)d_in[3];
    const float* u           = (const float*)d_in[4];
    const float* v           = (const float*)d_in[5];
    const float* ln_gamma    = (const float*)d_in[6];
    const float* ln_beta     = (const float*)d_in[7];
    const int*   src_idx     = (const int*)d_in[8];
    const int*   dst_idx     = (const int*)d_in[9];
    float* out = (float*)d_out;

    int E     = in_sizes[2];
    int n_src = in_sizes[0] / 256;   // N_SRC (T*C = 256)
    int n_dst = in_sizes[1] / 256;   // N_DST

    // Workspace layout
    float* h_srcT    = (float*)d_ws;                            // (n_src+1)*256
    float* h_base    = h_srcT + (size_t)(n_src + 1) * 256;      // n_dst*256
    float* h_dst_v   = h_base + (size_t)n_dst * 256;            // n_dst*256
    float* ew_sorted = h_dst_v + (size_t)n_dst * 256;           // E
    int*   src_sorted= (int*)(ew_sorted + E);                   // E
    int*   counts    = src_sorted + E;                          // n_dst
    int*   offsets   = counts + n_dst;                          // n_dst+1
    int*   cursor    = offsets + n_dst + 1;                     // n_dst

    int nsb = (n_src * 4 + 63) / 64;   // 625
    int ndb = (n_dst * 4 + 63) / 64;   // 625

    proj_kernel<<<nsb + ndb, 256, 0, stream>>>(feat_src, feat_dst, u, v,
                                               h_srcT, h_base, h_dst_v,
                                               counts, n_src, n_dst);
    hist_kernel<<<(E + 255) / 256, 256, 0, stream>>>(dst_idx, E, counts);
    scan_kernel<<<1, 1024, 0, stream>>>(counts, n_dst, offsets, cursor);
    scatter_kernel<<<(E + 255) / 256, 256, 0, stream>>>(src_idx, dst_idx, edge_weight, E,
                                                        cursor, src_sorted, ew_sorted);
    aggregate_kernel<<<n_dst / 4, 256, 0, stream>>>((const float4*)h_srcT, h_dst_v, h_base,
                                                    feat_dst, weight_e,
                                                    offsets, src_sorted, ew_sorted,
                                                    ln_gamma, ln_beta, out, n_src);
}